// Round 8
// baseline (110.024 us; speedup 1.0000x reference)
//
#include <hip/hip_runtime.h>
#include <hip/hip_bf16.h>

#define B_ 2
#define L_ 2048
#define H_ 8
#define D_ 64
#define SP_ 65       // STRIDE+1
#define NC_ 128      // level-1 chunks (16 rows each)
#define NH_ 16       // level-2 chunks (128 rows each)
#define RS_ 512      // H_*D_ floats between consecutive seq rows

typedef __attribute__((ext_vector_type(8))) short bf16x8;
typedef __attribute__((ext_vector_type(16))) float f32x16;

static __device__ inline short f2bf(float x) {
    return __builtin_bit_cast(short, __float2bfloat16(x));
}

static __device__ inline bf16x8 ld8_bf16(const float* __restrict__ p) {
    float4 a = *(const float4*)p;
    float4 b = *(const float4*)(p + 4);
    bf16x8 r;
    r[0]=f2bf(a.x); r[1]=f2bf(a.y); r[2]=f2bf(a.z); r[3]=f2bf(a.w);
    r[4]=f2bf(b.x); r[5]=f2bf(b.y); r[6]=f2bf(b.z); r[7]=f2bf(b.w);
    return r;
}

static __device__ inline bf16x8 ones_frag() {
    bf16x8 r;
    short o = f2bf(1.f);
    #pragma unroll
    for (int t = 0; t < 8; ++t) r[t] = o;
    return r;
}

// ================= Launch A: strided residue units + fused csum =============
// blk < 260 : strided residue units (4 waves/block, 1040 units) -> pB, zB
// blk < 324 : fused csum units (4 waves/block, 256 units): each 128-row unit
//             writes its 8 csum1 chunks AND csumH (single V pass).
__global__ __launch_bounds__(256) void pre_k(const float* __restrict__ q,
                                             const float* __restrict__ kk,
                                             const float* __restrict__ v,
                                             float* __restrict__ csum1,
                                             float* __restrict__ csumH,
                                             float* __restrict__ pB,
                                             float* __restrict__ zB) {
    __shared__ float LDS[4608];          // strided: 4 x 32x36
    int wib  = threadIdx.x >> 6;
    int lane = threadIdx.x & 63;
    int half = lane >> 5, ln = lane & 31;
    int blk  = blockIdx.x;

    if (blk < 260) {
        // ---------- strided residue class mod 65: rows l = r + 65*s, s=0..31
        int us = blk * 4 + wib;          // 0..1039
        int bh = us / SP_;
        int r  = us % SP_;
        int h = bh & 7, b = bh >> 3;
        const size_t base = (size_t)b * L_ * RS_ + (size_t)h * D_;
        float* Pw = LDS + wib * 1152;    // [32][36]

        bf16x8 bv0[2], bv1[2];
        #pragma unroll
        for (int kb = 0; kb < 2; ++kb) {
            int k0 = kb * 16 + half * 8;
            #pragma unroll
            for (int jj = 0; jj < 8; ++jj) {
                int lv = r + SP_ * (k0 + jj);
                lv = lv > L_ - 1 ? L_ - 1 : lv;
                const float* vr = v + base + (size_t)lv * RS_;
                bv0[kb][jj] = f2bf(vr[ln]);
                bv1[kb][jj] = f2bf(vr[32 + ln]);
            }
        }

        int lq = r + SP_ * ln;
        int lqc = lq > L_ - 1 ? L_ - 1 : lq;
        const float* qrow = q  + base + (size_t)lqc * RS_;
        const float* krow = kk + base + (size_t)lqc * RS_;
        f32x16 acc = {};
        #pragma unroll
        for (int kb = 0; kb < 4; ++kb) {
            bf16x8 a  = ld8_bf16(qrow + kb * 16 + half * 8);
            bf16x8 bb = ld8_bf16(krow + kb * 16 + half * 8);
            acc = __builtin_amdgcn_mfma_f32_32x32x16_bf16(a, bb, acc, 0, 0, 0);
        }
        #pragma unroll
        for (int rg = 0; rg < 16; ++rg) {
            int m = (rg & 3) + 8 * (rg >> 2) + 4 * half;
            bool act = (ln < m) && (r + SP_ * m < L_);
            Pw[m * 36 + ln] = act ? (__expf(0.125f * acc[rg]) - 1.f) : 0.f;
        }
        __syncthreads();

        f32x16 p0 = {}; f32x16 p1 = {}; f32x16 po = {};
        bf16x8 ones = ones_frag();
        #pragma unroll
        for (int kb = 0; kb < 2; ++kb) {
            int k0 = kb * 16 + half * 8;
            const float* pr = &Pw[ln * 36 + k0];
            float4 x = *(const float4*)pr;
            float4 y = *(const float4*)(pr + 4);
            bf16x8 ap;
            ap[0]=f2bf(x.x); ap[1]=f2bf(x.y); ap[2]=f2bf(x.z); ap[3]=f2bf(x.w);
            ap[4]=f2bf(y.x); ap[5]=f2bf(y.y); ap[6]=f2bf(y.z); ap[7]=f2bf(y.w);
            p0 = __builtin_amdgcn_mfma_f32_32x32x16_bf16(ap, bv0[kb], p0, 0, 0, 0);
            p1 = __builtin_amdgcn_mfma_f32_32x32x16_bf16(ap, bv1[kb], p1, 0, 0, 0);
            po = __builtin_amdgcn_mfma_f32_32x32x16_bf16(ap, ones,    po, 0, 0, 0);
        }
        float* pBr = pB + (size_t)bh * L_ * D_;
        float* zBr = zB + (size_t)bh * L_;
        #pragma unroll
        for (int rg = 0; rg < 16; ++rg) {
            int m = (rg & 3) + 8 * (rg >> 2) + 4 * half;
            int l = r + SP_ * m;
            if (l < L_) {
                pBr[(size_t)l * D_ + ln]      = p0[rg];
                pBr[(size_t)l * D_ + 32 + ln] = p1[rg];
                if (ln == 0) zBr[l] = po[rg];
            }
        }
    } else {
        // ---------- fused csum: one 128-row unit writes 8 csum1 + 1 csumH
        int uc = (blk - 260) * 4 + wib;  // 0..255 = bh*16 + cH
        int cH = uc & (NH_ - 1);
        int bh = uc >> 4;
        int h = bh & 7, b = bh >> 3;
        const float* vb = v + (size_t)(b * L_ + cH * 128) * RS_ + h * D_ + lane;
        float* c1p = csum1 + ((size_t)bh * NC_ + cH * 8) * D_ + lane;
        float hs = 0.f;
        #pragma unroll
        for (int c = 0; c < 8; ++c) {
            float s0 = 0.f, s1 = 0.f, s2 = 0.f, s3 = 0.f;
            #pragma unroll
            for (int l = 0; l < 16; l += 4) {
                s0 += vb[(c * 16 + l + 0) * RS_]; s1 += vb[(c * 16 + l + 1) * RS_];
                s2 += vb[(c * 16 + l + 2) * RS_]; s3 += vb[(c * 16 + l + 3) * RS_];
            }
            float s = (s0 + s1) + (s2 + s3);
            c1p[c * D_] = s;
            hs += s;
        }
        csumH[((size_t)bh * NH_ + cH) * D_ + lane] = hs;
    }
}

// ================= Launch B: local band MFMA + in-register finalize =========
// 512 blocks x 2 teams: team = local 32-row tile. After the band MFMA, the
// team finalizes its own rows (prefix from csum1/csumH, pB/zB from launch A)
// and writes out directly. pA/zA and the combine kernel are eliminated.
__global__ __launch_bounds__(256) void local_k(const float* __restrict__ q,
                                               const float* __restrict__ kk,
                                               const float* __restrict__ v,
                                               const float* __restrict__ csum1,
                                               const float* __restrict__ csumH,
                                               const float* __restrict__ pB,
                                               const float* __restrict__ zB,
                                               float* __restrict__ out) {
    __shared__ float LDS[4672];          // Pw 2x[32][68] @0; PF 2x[2][64] @4352; ZW 2x[32] @4608
    int wib  = threadIdx.x >> 6;
    int lane = threadIdx.x & 63;
    int half = lane >> 5, ln = lane & 31;
    // XCD-chunked swizzle (512 = 8 XCDs x 64): contiguous tiles per XCD ->
    // overlapping K/V bands hit the same L2.
    int wid = (blockIdx.x & 7) * 64 + (blockIdx.x >> 3);

    int tb = wib >> 1;
    int hf = wib & 1;
    int team = wid * 2 + tb;             // 0..1023
    int bh = team >> 6;
    int T  = (team & 63) << 5;
    int h = bh & 7, b = bh >> 3;
    const size_t base = (size_t)b * L_ * RS_ + (size_t)h * D_;
    float* Pw = LDS + tb * 2176;         // [32][68]
    float* PF = LDS + 4352 + tb * 128;   // [2][64]: P0, P1
    float* ZW = LDS + 4608 + tb * 32;    // [32]: band z per row
    int d0 = 32 * hf;

    // V prefetch: band rows, this wave's dims [d0, d0+32)
    bf16x8 bv[4];
    #pragma unroll
    for (int kb = 0; kb < 4; ++kb) {
        #pragma unroll
        for (int jj = 0; jj < 8; ++jj) {
            int jr = T - 16 + kb * 16 + half * 8 + jj;
            jr = jr < 0 ? 0 : (jr > L_ - 1 ? L_ - 1 : jr);
            bv[kb][jj] = f2bf(v[base + (size_t)jr * RS_ + d0 + ln]);
        }
    }

    // QK^T for this wave's 32-col tile
    const float* qrow = q + base + (size_t)(T + ln) * RS_;
    bf16x8 aq[4];
    #pragma unroll
    for (int kb = 0; kb < 4; ++kb) aq[kb] = ld8_bf16(qrow + kb * 16 + half * 8);

    int j = T - 16 + d0 + ln;
    j = j < 0 ? 0 : (j > L_ - 1 ? L_ - 1 : j);
    const float* krow = kk + base + (size_t)j * RS_;
    f32x16 acc = {};
    #pragma unroll
    for (int kb = 0; kb < 4; ++kb) {
        bf16x8 kf = ld8_bf16(krow + kb * 16 + half * 8);
        acc = __builtin_amdgcn_mfma_f32_32x32x16_bf16(aq[kb], kf, acc, 0, 0, 0);
    }

    // weights (exp-1 masked + "+1" prefix fold) into this wave's col half
    #pragma unroll
    for (int r = 0; r < 16; ++r) {
        int m = (r & 3) + 8 * (r >> 2) + 4 * half;
        float w;
        if (hf == 0) {
            bool act = (ln >= m) && (ln <= m + 16) && (T - 16 + ln >= 0);
            w = act ? (__expf(0.125f * acc[r]) - 1.f) : 0.f;
            if ((m < 16) && (ln >= 16) && (ln <= m + 16)) w += 1.f;
        } else {
            bool act = (ln <= m - 16);
            w = act ? (__expf(0.125f * acc[r]) - 1.f) : 0.f;
            if ((m >= 16) && (ln <= m - 16)) w += 1.f;
        }
        Pw[m * 68 + d0 + ln] = w;
    }

    // hf==0 wave: hierarchical prefix for this tile (2 values x 64 dims)
    if (hf == 0) {
        int c1 = T >> 4;                 // 16-row chunks below T (0..126)
        int nH = c1 >> 3, nR = c1 & 7;
        const float* csH = csumH + (size_t)bh * NH_ * D_ + lane;
        const float* cs1 = csum1 + ((size_t)bh * NC_ + (c1 & ~7)) * D_ + lane;
        float s0 = 0.f, s1 = 0.f, s2 = 0.f, s3 = 0.f;
        int cc = 0;
        for (; cc + 4 <= nH; cc += 4) {
            s0 += csH[(cc + 0) * D_]; s1 += csH[(cc + 1) * D_];
            s2 += csH[(cc + 2) * D_]; s3 += csH[(cc + 3) * D_];
        }
        for (; cc < nH; ++cc) s0 += csH[cc * D_];
        for (int t = 0; t < nR; ++t) {
            if (t & 1) s1 += cs1[t * D_]; else s2 += cs1[t * D_];
        }
        float P0 = (s0 + s1) + (s2 + s3);
        float P1 = P0 + csum1[((size_t)bh * NC_ + c1) * D_ + lane];
        PF[lane]      = P0;
        PF[64 + lane] = P1;
    }
    __syncthreads();

    // prefetch pB/zB for this wave's rows (L3-hot from launch A) — issued
    // before PV so the loads overlap the MFMA chain.
    const float* pBr = pB + (size_t)bh * L_ * D_;
    const float* zBr = zB + (size_t)bh * L_;
    float pbv[16], zbv[16];
    #pragma unroll
    for (int r = 0; r < 16; ++r) {
        int m = (r & 3) + 8 * (r >> 2) + 4 * half;
        int i = T + m;
        pbv[r] = pBr[(size_t)i * D_ + d0 + ln];
        zbv[r] = zBr[i];
    }

    // PV over full 64-col band, this wave's 32 output dims (+ po on hf==1)
    f32x16 p = {}; f32x16 po = {};
    bf16x8 ones = ones_frag();
    #pragma unroll
    for (int kb = 0; kb < 4; ++kb) {
        int k0 = kb * 16 + half * 8;
        const float* pr = &Pw[ln * 68 + k0];
        float4 x = *(const float4*)pr;
        float4 y = *(const float4*)(pr + 4);
        bf16x8 ap;
        ap[0]=f2bf(x.x); ap[1]=f2bf(x.y); ap[2]=f2bf(x.z); ap[3]=f2bf(x.w);
        ap[4]=f2bf(y.x); ap[5]=f2bf(y.y); ap[6]=f2bf(y.z); ap[7]=f2bf(y.w);
        p = __builtin_amdgcn_mfma_f32_32x32x16_bf16(ap, bv[kb], p, 0, 0, 0);
        if (hf == 1)
            po = __builtin_amdgcn_mfma_f32_32x32x16_bf16(ap, ones, po, 0, 0, 0);
    }

    // hf==1 publishes the band denominator per row
    if (hf == 1) {
        #pragma unroll
        for (int r = 0; r < 16; ++r) {
            int m = (r & 3) + 8 * (r >> 2) + 4 * half;
            if (ln == 0) ZW[m] = po[r] - (float)((m & 15) + 1);
        }
    }
    __syncthreads();

    // finalize: out = (band + strided + prefix) / z, straight from registers
    float Pf0 = PF[d0 + ln];
    float Pf1 = PF[64 + d0 + ln];
    #pragma unroll
    for (int r = 0; r < 16; ++r) {
        int m = (r & 3) + 8 * (r >> 2) + 4 * half;
        int i = T + m;
        float z   = ZW[m] + zbv[r] + (float)(i + 1);
        float num = p[r] + pbv[r] + (m < 16 ? Pf0 : Pf1);
        out[base + (size_t)i * RS_ + d0 + ln] = num / z;
    }
}

extern "C" void kernel_launch(void* const* d_in, const int* in_sizes, int n_in,
                              void* d_out, int out_size, void* d_ws, size_t ws_size,
                              hipStream_t stream) {
    const float* q = (const float*)d_in[0];
    const float* k = (const float*)d_in[1];
    const float* v = (const float*)d_in[2];
    // d_in[3] = attn_mask: deterministic causal — not read.
    float* out = (float*)d_out;

    float* csum1 = (float*)d_ws;                          // 131072 f
    float* pB    = csum1 + (size_t)B_ * H_ * NC_ * D_;    // 2097152 f
    float* zB    = pB    + (size_t)B_ * H_ * L_ * D_;     // 32768 f
    float* csumH = zB    + (size_t)B_ * H_ * L_;          // 16384 f

    // Launch A: 260 strided + 64 fused-csum blocks
    pre_k<<<324, 256, 0, stream>>>(q, k, v, csum1, csumH, pB, zB);
    // Launch B: 512 blocks (1024 local tiles), finalize fused
    local_k<<<512, 256, 0, stream>>>(q, k, v, csum1, csumH, pB, zB, out);
}